// Round 10
// baseline (248.362 us; speedup 1.0000x reference)
//
#include <hip/hip_runtime.h>
#include <hip/hip_bf16.h>
#include <stdint.h>

// Problem constants (ManualMHA): B=2, T=2048, D=1024, H=16, DK=64
#define B_   2
#define T_   2048
#define D_   1024
#define H_   16
#define DK_  64
#define KL2_ 0.18033688f   // SCALE * log2(e) = 0.125 * 1.4426950408889634

typedef __attribute__((ext_vector_type(8))) short   short8;   // 8 x bf16 (4 VGPRs)
typedef __attribute__((ext_vector_type(4))) float   floatx4;  // MFMA C/D
typedef unsigned short ushort_t;
typedef unsigned int   uint_t;

// ---------------------------------------------------------------- helpers
__device__ __forceinline__ ushort_t f32_to_bf16(float f) {
    union { float f; unsigned int u; } v; v.f = f;
    unsigned int r = v.u + 0x7fffu + ((v.u >> 16) & 1u);   // RNE
    return (ushort_t)(r >> 16);
}

// pack two fp32 -> (bf16(hi)<<16)|bf16(lo) with +0x8000 round bias, 3 VALU ops
__device__ __forceinline__ uint_t pk_bf16(float lo, float hi) {
    uint_t ulo = __builtin_bit_cast(uint_t, lo) + 0x8000u;
    uint_t uhi = __builtin_bit_cast(uint_t, hi) + 0x8000u;
    return __builtin_amdgcn_perm(uhi, ulo, 0x07060302);  // bytes: lo[2],lo[3],hi[2],hi[3]
}

__device__ __forceinline__ void async_copy16(const ushort_t* g, ushort_t* l) {
    typedef const unsigned int __attribute__((address_space(1)))* gp_t;
    typedef       unsigned int __attribute__((address_space(3)))* lp_t;
    __builtin_amdgcn_global_load_lds((gp_t)(uintptr_t)g, (lp_t)(uintptr_t)l, 16, 0, 0);
}

// ---------------------------------------------------------------- fused fp32 -> bf16 cast
__global__ __launch_bounds__(256) void cast_all_kernel(
    const float* __restrict__ q, const float* __restrict__ k, const float* __restrict__ v,
    const float* __restrict__ wq, const float* __restrict__ wk,
    const float* __restrict__ wv, const float* __restrict__ wo,
    ushort_t* __restrict__ oq, ushort_t* __restrict__ ok, ushort_t* __restrict__ ov,
    ushort_t* __restrict__ owq, ushort_t* __restrict__ owk,
    ushort_t* __restrict__ owv, ushort_t* __restrict__ owo)
{
    const int NTD4 = (B_ * T_ * D_) / 4;   // 1048576
    const int NW4  = (D_ * D_) / 4;        // 262144
    int i = blockIdx.x * 256 + threadIdx.x;
    const float* s; ushort_t* d; int off;
    if (i < NTD4)              { s = q; d = oq; off = i; }
    else if (i < 2 * NTD4)     { s = k; d = ok; off = i - NTD4; }
    else if (i < 3 * NTD4)     { s = v; d = ov; off = i - 2 * NTD4; }
    else {
        int w = i - 3 * NTD4;
        int seg = w / NW4;  off = w - seg * NW4;
        s = (seg == 0) ? wq : (seg == 1) ? wk : (seg == 2) ? wv : wo;
        d = (seg == 0) ? owq : (seg == 1) ? owk : (seg == 2) ? owv : owo;
    }
    float4 x = ((const float4*)s)[off];
    ushort4 o;
    o.x = f32_to_bf16(x.x); o.y = f32_to_bf16(x.y);
    o.z = f32_to_bf16(x.z); o.w = f32_to_bf16(x.w);
    ((ushort4*)d)[off] = o;
}

// ---------------------------------------------------------------- GEMM (C = A * W^T + bias)
// MODE 0: out fp32 [M,N]
// MODE 1: out bf16 scattered to [B,H,T,DK], scaled by oscale       (Q, K)
// MODE 2: out bf16 scattered to [B,H,DK,T] with t[5:4]<->t[3:2]    (V, attn A-frag layout)
//
// Structure = R8 (m97 shape: stage, sync, compute, sync — the 2-barrier form;
// R9's 1-barrier dbuf regressed 48->66 us, the compiler needs the explicit
// barrier pair to keep the prefetch early). Layout = R9's CHUNK-MAJOR
// [chunk(4)][row(128)], 16B slots: fragment read addr = (qd*128+row)*16B ->
// lane bank start = cl*4 % 32, 8 phases x 8 lanes = conflict-free (R9
// measured 0 vs R8's 3.1M conflict cycles). Staging dest = base + tid*16
// (wave-uniform rule); each thread fetches the global chunk for its slot.
#define BM 128
#define BN 128
#define BK 32

template<int MODE>
__device__ __forceinline__ void gemm_bt_device(
    const ushort_t* __restrict__ A, const ushort_t* __restrict__ W,
    const float* __restrict__ bias, void* __restrict__ outp,
    int m0, int n0, ushort_t* sm, float oscale)
{
    const int tid  = threadIdx.x;
    const int lane = tid & 63;
    const int wv   = tid >> 6;
    const int wm   = (wv >> 1) * 64;
    const int wn   = (wv & 1) * 64;
    const int cl   = lane & 15;
    const int qd   = lane >> 4;

    floatx4 acc[4][4];
    const floatx4 z4 = {0.f, 0.f, 0.f, 0.f};
    #pragma unroll
    for (int mi = 0; mi < 4; ++mi)
        #pragma unroll
        for (int ni = 0; ni < 4; ++ni) acc[mi][ni] = z4;

    // staging slots: thread handles slots {tid, tid+256} of each operand;
    // slot s -> chunk = s>>7, row = s&127; global = base + row*1024 + chunk*8
    const int s1  = tid + 256;
    const int ar0 = tid & 127, ac0 = tid >> 7;
    const int ar1 = s1 & 127,  ac1 = s1 >> 7;
    const ushort_t* Ag0 = A + (size_t)(m0 + ar0) * 1024 + ac0 * 8;
    const ushort_t* Ag1 = A + (size_t)(m0 + ar1) * 1024 + ac1 * 8;
    const ushort_t* Wg0 = W + (size_t)(n0 + ar0) * 1024 + ac0 * 8;
    const ushort_t* Wg1 = W + (size_t)(n0 + ar1) * 1024 + ac1 * 8;

    for (int k0 = 0; k0 < 1024; k0 += BK) {
        async_copy16(Ag0 + k0, sm + tid * 8);
        async_copy16(Ag1 + k0, sm + s1 * 8);
        async_copy16(Wg0 + k0, sm + 4096 + tid * 8);
        async_copy16(Wg1 + k0, sm + 4096 + s1 * 8);
        __syncthreads();

        short8 af[4], bfr[4];
        #pragma unroll
        for (int mi = 0; mi < 4; ++mi)
            af[mi] = *(const short8*)(sm + (qd * 128 + wm + mi * 16 + cl) * 8);
        #pragma unroll
        for (int ni = 0; ni < 4; ++ni)
            bfr[ni] = *(const short8*)(sm + 4096 + (qd * 128 + wn + ni * 16 + cl) * 8);

        #pragma unroll
        for (int mi = 0; mi < 4; ++mi)
            #pragma unroll
            for (int ni = 0; ni < 4; ++ni)
                acc[mi][ni] = __builtin_amdgcn_mfma_f32_16x16x32_bf16(
                    af[mi], bfr[ni], acc[mi][ni], 0, 0, 0);
        __syncthreads();
    }

    // epilogue: C/D layout col = lane&15, row = (lane>>4)*4 + reg
    #pragma unroll
    for (int mi = 0; mi < 4; ++mi) {
        #pragma unroll
        for (int ni = 0; ni < 4; ++ni) {
            const int n = n0 + wn + ni * 16 + cl;
            const float bn = bias[n];
            if (MODE == 0) {
                float* out = (float*)outp;
                #pragma unroll
                for (int r = 0; r < 4; ++r) {
                    const int m = m0 + wm + mi * 16 + qd * 4 + r;
                    out[(size_t)m * D_ + n] = acc[mi][ni][r] + bn;
                }
            } else if (MODE == 1) {
                ushort_t* out = (ushort_t*)outp;
                const int h = n >> 6, dk = n & 63;
                #pragma unroll
                for (int r = 0; r < 4; ++r) {
                    const int m = m0 + wm + mi * 16 + qd * 4 + r;
                    const int b = m >> 11, t = m & (T_ - 1);
                    out[(((size_t)(b * H_ + h)) * T_ + t) * DK_ + dk] =
                        f32_to_bf16((acc[mi][ni][r] + bn) * oscale);
                }
            } else {
                ushort_t* out = (ushort_t*)outp;
                const int h = n >> 6, dk = n & 63;
                const int mb = m0 + wm + mi * 16 + qd * 4;  // 4 consecutive t, same b
                const int b = mb >> 11, t0 = mb & (T_ - 1);
                // swizzle t bits [5:4] <-> [3:2] so attention A-fragments are contiguous
                const int tsw = (t0 & ~60) | ((t0 & 48) >> 2) | ((t0 & 12) << 2);
                ushort4 o;
                o.x = f32_to_bf16(acc[mi][ni][0] + bn);
                o.y = f32_to_bf16(acc[mi][ni][1] + bn);
                o.z = f32_to_bf16(acc[mi][ni][2] + bn);
                o.w = f32_to_bf16(acc[mi][ni][3] + bn);
                *(ushort4*)(out + (((size_t)(b * H_ + h)) * DK_ + dk) * T_ + tsw) = o;
            }
        }
    }
}

__global__ __launch_bounds__(256) void gemm_qkv_kernel(
    const ushort_t* __restrict__ Xq, const ushort_t* __restrict__ Xk, const ushort_t* __restrict__ Xv,
    const ushort_t* __restrict__ Wq, const ushort_t* __restrict__ Wk, const ushort_t* __restrict__ Wv,
    const float* __restrict__ bq, const float* __restrict__ bk, const float* __restrict__ bv,
    ushort_t* __restrict__ Q, ushort_t* __restrict__ K, ushort_t* __restrict__ Vt)
{
    __shared__ __align__(16) ushort_t sm[8192];   // A 8KB + B 8KB (single buffer)
    const int m0 = blockIdx.x * BM, n0 = blockIdx.y * BN;
    // Q is pre-scaled by SCALE*log2(e) so attention's softmax is a bare exp2
    if (blockIdx.z == 0)      gemm_bt_device<1>(Xq, Wq, bq, Q,  m0, n0, sm, KL2_);
    else if (blockIdx.z == 1) gemm_bt_device<1>(Xk, Wk, bk, K,  m0, n0, sm, 1.0f);
    else                      gemm_bt_device<2>(Xv, Wv, bv, Vt, m0, n0, sm, 1.0f);
}

__global__ __launch_bounds__(256) void gemm_o_kernel(
    const ushort_t* __restrict__ A, const ushort_t* __restrict__ W,
    const float* __restrict__ bias, float* __restrict__ out)
{
    __shared__ __align__(16) ushort_t sm[8192];
    gemm_bt_device<0>(A, W, bias, out, blockIdx.x * BM, blockIdx.y * BN, sm, 1.0f);
}

// ---------------------------------------------------------------- flash attention
// (unchanged from R8 — 4 LDS buffers, two steps per barrier, pair-balanced)
__global__ __launch_bounds__(256, 2) void attn_kernel(
    const ushort_t* __restrict__ Q, const ushort_t* __restrict__ K,
    const ushort_t* __restrict__ Vs, ushort_t* __restrict__ O)
{
    __shared__ __align__(16) ushort_t sm[32768];  // 4 bufs x (K 4096 + V 4096)
    const int tid  = threadIdx.x;
    const int lane = tid & 63;
    const int wv   = tid >> 6;
    const int cl   = lane & 15;
    const int qd   = lane >> 4;
    const int swz  = cl & 7;
    const int h = blockIdx.x & (H_ - 1), b = blockIdx.x >> 4;
    const int p   = blockIdx.y;          // pair id 0..15
    const int btA = 31 - p;              // deep 64-row tile; tile B = p

    const ushort_t* Qh = Q  + ((size_t)(b * H_ + h) * T_) * DK_;
    const ushort_t* Kh = K  + ((size_t)(b * H_ + h) * T_) * DK_;
    const ushort_t* Vh = Vs + ((size_t)(b * H_ + h) * DK_) * T_;

    const int sr  = tid >> 3;
    const int sc  = tid & 7;
    const int scg = sc ^ (sr & 7);

    auto stage_step = [&](int s) {
        const int kbase = ((s <= btA) ? s : (s - btA - 1)) << 6;
        ushort_t* Kb = sm + (s & 3) * 8192;
        ushort_t* Vb = Kb + 4096;
        #pragma unroll
        for (int rr = 0; rr < 2; ++rr) {
            const int r = rr * 32 + sr;
            async_copy16(Kh + (size_t)(kbase + r) * DK_ + scg * 8, Kb + r * 64 + sc * 8);
            async_copy16(Vh + (size_t)r * T_ + kbase + scg * 8,    Vb + r * 64 + sc * 8);
        }
    };

    int qw = btA * 64 + wv * 16;         // wave's q-row base (current tile)
    short8 qf0 = *(const short8*)(Qh + (size_t)(qw + cl) * DK_ + qd * 8);
    short8 qf1 = *(const short8*)(Qh + (size_t)(qw + cl) * DK_ + 32 + qd * 8);

    stage_step(0);
    stage_step(1);

    const floatx4 z4 = {0.f, 0.f, 0.f, 0.f};
    floatx4 oaccT[4] = {z4, z4, z4, z4}; // O^T tiles: row = dk, col = q
    float l_ = 0.f;

    auto flush = [&](int q0w) {
        float l = l_;
        l += __shfl_xor(l, 16, 64);
        l += __shfl_xor(l, 32, 64);
        const float inv = 1.0f / l;
        ushort_t* Ob = O + ((size_t)(b * T_ + q0w + cl)) * D_ + h * DK_ + qd * 4;
        #pragma unroll
        for (int dt = 0; dt < 4; ++dt) {
            ushort4 o;
            o.x = f32_to_bf16(oaccT[dt][0] * inv);
            o.y = f32_to_bf16(oaccT[dt][1] * inv);
            o.z = f32_to_bf16(oaccT[dt][2] * inv);
            o.w = f32_to_bf16(oaccT[dt][3] * inv);
            *(ushort4*)(Ob + dt * 16) = o;
        }
    };

    auto compute_step = [&](int s) {
        const bool inA  = (s <= btA);
        const int kbase = (inA ? s : (s - btA - 1)) << 6;
        const bool diag = inA ? (s == btA) : (s == 32);
        ushort_t* cb = sm + (s & 3) * 8192;
        short8 kb[4][2];
        #pragma unroll
        for (int m = 0; m < 4; ++m)
            #pragma unroll
            for (int i = 0; i < 2; ++i)
                kb[m][i] = *(const short8*)(cb + (m * 16 + cl) * 64 + ((i * 4 + qd) ^ swz) * 8);
        floatx4 sacc[4] = {z4, z4, z4, z4};
        #pragma unroll
        for (int i = 0; i < 2; ++i)
            #pragma unroll
            for (int m = 0; m < 4; ++m)
                sacc[m] = __builtin_amdgcn_mfma_f32_16x16x32_bf16(
                    kb[m][i], (i ? qf1 : qf0), sacc[m], 0, 0, 0);
        const int qabs = qw + cl;
        float pr[4][4];
        if (diag) {
            #pragma unroll
            for (int c = 0; c < 4; ++c)
                #pragma unroll
                for (int r = 0; r < 4; ++r) {
                    const bool keep = (kbase + c * 16 + qd * 4 + r) <= qabs;
                    const float e = __builtin_amdgcn_exp2f(sacc[c][r]);
                    pr[c][r] = keep ? e : 0.f;
                    l_ += pr[c][r];
                }
        } else {
            #pragma unroll
            for (int c = 0; c < 4; ++c)
                #pragma unroll
                for (int r = 0; r < 4; ++r) {
                    pr[c][r] = __builtin_amdgcn_exp2f(sacc[c][r]);
                    l_ += pr[c][r];
                }
        }
        short8 va2[4][2];
        #pragma unroll
        for (int dt = 0; dt < 4; ++dt)
            #pragma unroll
            for (int h2 = 0; h2 < 2; ++h2)
                va2[dt][h2] = *(const short8*)(cb + 4096 + (dt * 16 + cl) * 64 +
                                               ((qd * 2 + h2) ^ swz) * 8);
        #pragma unroll
        for (int cp = 0; cp < 2; ++cp) {
            union { uint_t u[4]; short8 v; } pb;
            pb.u[0] = pk_bf16(pr[cp * 2][0],     pr[cp * 2][1]);
            pb.u[1] = pk_bf16(pr[cp * 2][2],     pr[cp * 2][3]);
            pb.u[2] = pk_bf16(pr[cp * 2 + 1][0], pr[cp * 2 + 1][1]);
            pb.u[3] = pk_bf16(pr[cp * 2 + 1][2], pr[cp * 2 + 1][3]);
            #pragma unroll
            for (int dt = 0; dt < 4; ++dt)
                oaccT[dt] = __builtin_amdgcn_mfma_f32_16x16x32_bf16(
                    va2[dt][cp], pb.v, oaccT[dt], 0, 0, 0);
        }
        if (s == btA) {
            flush(qw);
            #pragma unroll
            for (int dt = 0; dt < 4; ++dt) oaccT[dt] = z4;
            l_ = 0.f;
            qw = p * 64 + wv * 16;
            qf0 = *(const short8*)(Qh + (size_t)(qw + cl) * DK_ + qd * 8);
            qf1 = *(const short8*)(Qh + (size_t)(qw + cl) * DK_ + 32 + qd * 8);
        }
    };

    for (int g = 0; g < 17; ++g) {
        const int s0 = g * 2;
        __syncthreads();
        if (s0 + 2 <= 32) stage_step(s0 + 2);
        if (s0 + 3 <= 32) stage_step(s0 + 3);
        compute_step(s0);
        if (s0 + 1 <= 32) compute_step(s0 + 1);
    }
    flush(qw);                           // tile B
}

// ---------------------------------------------------------------- launch
extern "C" void kernel_launch(void* const* d_in, const int* in_sizes, int n_in,
                              void* d_out, int out_size, void* d_ws, size_t ws_size,
                              hipStream_t stream)
{
    const float* q_in = (const float*)d_in[0];
    const float* k_in = (const float*)d_in[1];
    const float* v_in = (const float*)d_in[2];
    const float* Wq   = (const float*)d_in[3];
    const float* bq   = (const float*)d_in[4];
    const float* Wk   = (const float*)d_in[5];
    const float* bk   = (const float*)d_in[6];
    const float* Wv   = (const float*)d_in[7];
    const float* bv   = (const float*)d_in[8];
    const float* Wo   = (const float*)d_in[9];
    const float* bo   = (const float*)d_in[10];
    float* out = (float*)d_out;

    const size_t NTD = (size_t)B_ * T_ * D_;  // 4,194,304
    const size_t NW  = (size_t)D_ * D_;       // 1,048,576
    ushort_t* ws  = (ushort_t*)d_ws;
    ushort_t* Xq  = ws;
    ushort_t* Xk  = Xq + NTD;
    ushort_t* Xv  = Xk + NTD;
    ushort_t* Wqb = Xv + NTD;
    ushort_t* Wkb = Wqb + NW;
    ushort_t* Wvb = Wkb + NW;
    ushort_t* Wob = Wvb + NW;
    ushort_t* Qd  = Wob + NW;
    ushort_t* Kd  = Qd + NTD;
    ushort_t* Vtd = Kd + NTD;
    ushort_t* Od  = Vtd + NTD;

    const int total4 = (int)((3 * NTD + 4 * NW) / 4);   // 4,194,304
    cast_all_kernel<<<dim3(total4 / 256), dim3(256), 0, stream>>>(
        q_in, k_in, v_in, Wq, Wk, Wv, Wo,
        Xq, Xk, Xv, Wqb, Wkb, Wvb, Wob);

    gemm_qkv_kernel<<<dim3(32, 8, 3), dim3(256), 0, stream>>>(
        Xq, Xk, Xv, Wqb, Wkb, Wvb, bq, bk, bv, Qd, Kd, Vtd);

    attn_kernel<<<dim3(32, 16), dim3(256), 0, stream>>>(Qd, Kd, Vtd, Od);

    gemm_o_kernel<<<dim3(32, 8, 1), dim3(256), 0, stream>>>(Od, Wob, bo, out);
}

// Round 11
// 217.514 us; speedup vs baseline: 1.1418x; 1.1418x over previous
//
#include <hip/hip_runtime.h>
#include <hip/hip_bf16.h>
#include <stdint.h>

// Problem constants (ManualMHA): B=2, T=2048, D=1024, H=16, DK=64
#define B_   2
#define T_   2048
#define D_   1024
#define H_   16
#define DK_  64
#define KL2_ 0.18033688f   // SCALE * log2(e) = 0.125 * 1.4426950408889634

typedef __attribute__((ext_vector_type(8))) short   short8;   // 8 x bf16 (4 VGPRs)
typedef __attribute__((ext_vector_type(4))) float   floatx4;  // MFMA C/D
typedef unsigned short ushort_t;
typedef unsigned int   uint_t;

// ---------------------------------------------------------------- helpers
__device__ __forceinline__ ushort_t f32_to_bf16(float f) {
    union { float f; unsigned int u; } v; v.f = f;
    unsigned int r = v.u + 0x7fffu + ((v.u >> 16) & 1u);   // RNE
    return (ushort_t)(r >> 16);
}

// pack two fp32 -> (bf16(hi)<<16)|bf16(lo) with +0x8000 round bias, 3 VALU ops
__device__ __forceinline__ uint_t pk_bf16(float lo, float hi) {
    uint_t ulo = __builtin_bit_cast(uint_t, lo) + 0x8000u;
    uint_t uhi = __builtin_bit_cast(uint_t, hi) + 0x8000u;
    return __builtin_amdgcn_perm(uhi, ulo, 0x07060302);  // bytes: lo[2],lo[3],hi[2],hi[3]
}

__device__ __forceinline__ void async_copy16(const ushort_t* g, ushort_t* l) {
    typedef const unsigned int __attribute__((address_space(1)))* gp_t;
    typedef       unsigned int __attribute__((address_space(3)))* lp_t;
    __builtin_amdgcn_global_load_lds((gp_t)(uintptr_t)g, (lp_t)(uintptr_t)l, 16, 0, 0);
}

// ---------------------------------------------------------------- fused fp32 -> bf16 cast
__global__ __launch_bounds__(256) void cast_all_kernel(
    const float* __restrict__ q, const float* __restrict__ k, const float* __restrict__ v,
    const float* __restrict__ wq, const float* __restrict__ wk,
    const float* __restrict__ wv, const float* __restrict__ wo,
    ushort_t* __restrict__ oq, ushort_t* __restrict__ ok, ushort_t* __restrict__ ov,
    ushort_t* __restrict__ owq, ushort_t* __restrict__ owk,
    ushort_t* __restrict__ owv, ushort_t* __restrict__ owo)
{
    const int NTD4 = (B_ * T_ * D_) / 4;   // 1048576
    const int NW4  = (D_ * D_) / 4;        // 262144
    int i = blockIdx.x * 256 + threadIdx.x;
    const float* s; ushort_t* d; int off;
    if (i < NTD4)              { s = q; d = oq; off = i; }
    else if (i < 2 * NTD4)     { s = k; d = ok; off = i - NTD4; }
    else if (i < 3 * NTD4)     { s = v; d = ov; off = i - 2 * NTD4; }
    else {
        int w = i - 3 * NTD4;
        int seg = w / NW4;  off = w - seg * NW4;
        s = (seg == 0) ? wq : (seg == 1) ? wk : (seg == 2) ? wv : wo;
        d = (seg == 0) ? owq : (seg == 1) ? owk : (seg == 2) ? owv : owo;
    }
    float4 x = ((const float4*)s)[off];
    ushort4 o;
    o.x = f32_to_bf16(x.x); o.y = f32_to_bf16(x.y);
    o.z = f32_to_bf16(x.z); o.w = f32_to_bf16(x.w);
    ((ushort4*)d)[off] = o;
}

// ---------------------------------------------------------------- GEMM (C = A * W^T + bias)
// MODE 0: out fp32 [M,N]
// MODE 1: out bf16 scattered to [B,H,T,DK], scaled by oscale       (Q, K)
// MODE 2: out bf16 scattered to [B,H,DK,T] with t[5:4]<->t[3:2]    (V, attn A-frag layout)
//
// Structure = R8 (m97 2-barrier shape; R9's 1-barrier dbuf regressed).
// Layout   = R8 row-major [row][32] (staging fully coalesced: 4 lanes per
//            64B row segment; R10's chunk-major made lanes stride 2KB and
//            regressed 48->61 us) PLUS an XOR chunk swizzle:
//   stage:  LDS slot c of row r holds global chunk c ^ ((r>>1)&3)
//           (dest stays base + tid*16, wave-uniform rule; same 64B segment)
//   read:   fragment chunk' = qd ^ ((cl>>1)&3)   [(row>>1)&3 == (cl>>1)&3
//           since row = 16-aligned + cl]
//   banks:  for fixed qd the 16 cl-lanes hit (phase=cl&1, group=qd^((cl>>1)&3))
//           = exactly 2 lanes per 4-bank group -> 2-way = free (m136).
//           R8 unswizzled was 8 lanes/group: 3.1M conflict cycles.
#define BM 128
#define BN 128
#define BK 32

template<int MODE>
__device__ __forceinline__ void gemm_bt_device(
    const ushort_t* __restrict__ A, const ushort_t* __restrict__ W,
    const float* __restrict__ bias, void* __restrict__ outp,
    int m0, int n0, ushort_t* sm, float oscale)
{
    const int tid  = threadIdx.x;
    const int lane = tid & 63;
    const int wv   = tid >> 6;
    const int wm   = (wv >> 1) * 64;
    const int wn   = (wv & 1) * 64;
    const int cl   = lane & 15;
    const int qd   = lane >> 4;
    const int sw4  = (cl >> 1) & 3;      // fragment-read chunk swizzle

    floatx4 acc[4][4];
    const floatx4 z4 = {0.f, 0.f, 0.f, 0.f};
    #pragma unroll
    for (int mi = 0; mi < 4; ++mi)
        #pragma unroll
        for (int ni = 0; ni < 4; ++ni) acc[mi][ni] = z4;

    // staging: thread -> row r0 = tid>>2 (and r0+64), slot c = tid&3;
    // global chunk cg = c ^ ((r>>1)&3) (same for r and r+64: 32%4==0)
    const int r0 = tid >> 2;
    const int cg = (tid & 3) ^ ((r0 >> 1) & 3);
    const ushort_t* Ag0 = A + (size_t)(m0 + r0) * 1024 + cg * 8;
    const ushort_t* Ag1 = A + (size_t)(m0 + 64 + r0) * 1024 + cg * 8;
    const ushort_t* Wg0 = W + (size_t)(n0 + r0) * 1024 + cg * 8;
    const ushort_t* Wg1 = W + (size_t)(n0 + 64 + r0) * 1024 + cg * 8;
    ushort_t* As0 = sm + tid * 8;
    ushort_t* As1 = sm + 2048 + tid * 8;
    ushort_t* Bs0 = sm + 4096 + tid * 8;
    ushort_t* Bs1 = sm + 6144 + tid * 8;

    for (int k0 = 0; k0 < 1024; k0 += BK) {
        async_copy16(Ag0 + k0, As0);
        async_copy16(Ag1 + k0, As1);
        async_copy16(Wg0 + k0, Bs0);
        async_copy16(Wg1 + k0, Bs1);
        __syncthreads();

        short8 af[4], bfr[4];
        #pragma unroll
        for (int mi = 0; mi < 4; ++mi)
            af[mi] = *(const short8*)(sm + (wm + mi * 16 + cl) * 32 + (qd ^ sw4) * 8);
        #pragma unroll
        for (int ni = 0; ni < 4; ++ni)
            bfr[ni] = *(const short8*)(sm + 4096 + (wn + ni * 16 + cl) * 32 + (qd ^ sw4) * 8);

        #pragma unroll
        for (int mi = 0; mi < 4; ++mi)
            #pragma unroll
            for (int ni = 0; ni < 4; ++ni)
                acc[mi][ni] = __builtin_amdgcn_mfma_f32_16x16x32_bf16(
                    af[mi], bfr[ni], acc[mi][ni], 0, 0, 0);
        __syncthreads();
    }

    // epilogue: C/D layout col = lane&15, row = (lane>>4)*4 + reg
    #pragma unroll
    for (int mi = 0; mi < 4; ++mi) {
        #pragma unroll
        for (int ni = 0; ni < 4; ++ni) {
            const int n = n0 + wn + ni * 16 + cl;
            const float bn = bias[n];
            if (MODE == 0) {
                float* out = (float*)outp;
                #pragma unroll
                for (int r = 0; r < 4; ++r) {
                    const int m = m0 + wm + mi * 16 + qd * 4 + r;
                    out[(size_t)m * D_ + n] = acc[mi][ni][r] + bn;
                }
            } else if (MODE == 1) {
                ushort_t* out = (ushort_t*)outp;
                const int h = n >> 6, dk = n & 63;
                #pragma unroll
                for (int r = 0; r < 4; ++r) {
                    const int m = m0 + wm + mi * 16 + qd * 4 + r;
                    const int b = m >> 11, t = m & (T_ - 1);
                    out[(((size_t)(b * H_ + h)) * T_ + t) * DK_ + dk] =
                        f32_to_bf16((acc[mi][ni][r] + bn) * oscale);
                }
            } else {
                ushort_t* out = (ushort_t*)outp;
                const int h = n >> 6, dk = n & 63;
                const int mb = m0 + wm + mi * 16 + qd * 4;  // 4 consecutive t, same b
                const int b = mb >> 11, t0 = mb & (T_ - 1);
                // swizzle t bits [5:4] <-> [3:2] so attention A-fragments are contiguous
                const int tsw = (t0 & ~60) | ((t0 & 48) >> 2) | ((t0 & 12) << 2);
                ushort4 o;
                o.x = f32_to_bf16(acc[mi][ni][0] + bn);
                o.y = f32_to_bf16(acc[mi][ni][1] + bn);
                o.z = f32_to_bf16(acc[mi][ni][2] + bn);
                o.w = f32_to_bf16(acc[mi][ni][3] + bn);
                *(ushort4*)(out + (((size_t)(b * H_ + h)) * DK_ + dk) * T_ + tsw) = o;
            }
        }
    }
}

__global__ __launch_bounds__(256) void gemm_qkv_kernel(
    const ushort_t* __restrict__ Xq, const ushort_t* __restrict__ Xk, const ushort_t* __restrict__ Xv,
    const ushort_t* __restrict__ Wq, const ushort_t* __restrict__ Wk, const ushort_t* __restrict__ Wv,
    const float* __restrict__ bq, const float* __restrict__ bk, const float* __restrict__ bv,
    ushort_t* __restrict__ Q, ushort_t* __restrict__ K, ushort_t* __restrict__ Vt)
{
    __shared__ __align__(16) ushort_t sm[8192];   // A 8KB + B 8KB (single buffer)
    const int m0 = blockIdx.x * BM, n0 = blockIdx.y * BN;
    // Q is pre-scaled by SCALE*log2(e) so attention's softmax is a bare exp2
    if (blockIdx.z == 0)      gemm_bt_device<1>(Xq, Wq, bq, Q,  m0, n0, sm, KL2_);
    else if (blockIdx.z == 1) gemm_bt_device<1>(Xk, Wk, bk, K,  m0, n0, sm, 1.0f);
    else                      gemm_bt_device<2>(Xv, Wv, bv, Vt, m0, n0, sm, 1.0f);
}

__global__ __launch_bounds__(256) void gemm_o_kernel(
    const ushort_t* __restrict__ A, const ushort_t* __restrict__ W,
    const float* __restrict__ bias, float* __restrict__ out)
{
    __shared__ __align__(16) ushort_t sm[8192];
    gemm_bt_device<0>(A, W, bias, out, blockIdx.x * BM, blockIdx.y * BN, sm, 1.0f);
}

// ---------------------------------------------------------------- flash attention
// (unchanged from R8 — 4 LDS buffers, two steps per barrier, pair-balanced)
__global__ __launch_bounds__(256, 2) void attn_kernel(
    const ushort_t* __restrict__ Q, const ushort_t* __restrict__ K,
    const ushort_t* __restrict__ Vs, ushort_t* __restrict__ O)
{
    __shared__ __align__(16) ushort_t sm[32768];  // 4 bufs x (K 4096 + V 4096)
    const int tid  = threadIdx.x;
    const int lane = tid & 63;
    const int wv   = tid >> 6;
    const int cl   = lane & 15;
    const int qd   = lane >> 4;
    const int swz  = cl & 7;
    const int h = blockIdx.x & (H_ - 1), b = blockIdx.x >> 4;
    const int p   = blockIdx.y;          // pair id 0..15
    const int btA = 31 - p;              // deep 64-row tile; tile B = p

    const ushort_t* Qh = Q  + ((size_t)(b * H_ + h) * T_) * DK_;
    const ushort_t* Kh = K  + ((size_t)(b * H_ + h) * T_) * DK_;
    const ushort_t* Vh = Vs + ((size_t)(b * H_ + h) * DK_) * T_;

    const int sr  = tid >> 3;
    const int sc  = tid & 7;
    const int scg = sc ^ (sr & 7);

    auto stage_step = [&](int s) {
        const int kbase = ((s <= btA) ? s : (s - btA - 1)) << 6;
        ushort_t* Kb = sm + (s & 3) * 8192;
        ushort_t* Vb = Kb + 4096;
        #pragma unroll
        for (int rr = 0; rr < 2; ++rr) {
            const int r = rr * 32 + sr;
            async_copy16(Kh + (size_t)(kbase + r) * DK_ + scg * 8, Kb + r * 64 + sc * 8);
            async_copy16(Vh + (size_t)r * T_ + kbase + scg * 8,    Vb + r * 64 + sc * 8);
        }
    };

    int qw = btA * 64 + wv * 16;         // wave's q-row base (current tile)
    short8 qf0 = *(const short8*)(Qh + (size_t)(qw + cl) * DK_ + qd * 8);
    short8 qf1 = *(const short8*)(Qh + (size_t)(qw + cl) * DK_ + 32 + qd * 8);

    stage_step(0);
    stage_step(1);

    const floatx4 z4 = {0.f, 0.f, 0.f, 0.f};
    floatx4 oaccT[4] = {z4, z4, z4, z4}; // O^T tiles: row = dk, col = q
    float l_ = 0.f;

    auto flush = [&](int q0w) {
        float l = l_;
        l += __shfl_xor(l, 16, 64);
        l += __shfl_xor(l, 32, 64);
        const float inv = 1.0f / l;
        ushort_t* Ob = O + ((size_t)(b * T_ + q0w + cl)) * D_ + h * DK_ + qd * 4;
        #pragma unroll
        for (int dt = 0; dt < 4; ++dt) {
            ushort4 o;
            o.x = f32_to_bf16(oaccT[dt][0] * inv);
            o.y = f32_to_bf16(oaccT[dt][1] * inv);
            o.z = f32_to_bf16(oaccT[dt][2] * inv);
            o.w = f32_to_bf16(oaccT[dt][3] * inv);
            *(ushort4*)(Ob + dt * 16) = o;
        }
    };

    auto compute_step = [&](int s) {
        const bool inA  = (s <= btA);
        const int kbase = (inA ? s : (s - btA - 1)) << 6;
        const bool diag = inA ? (s == btA) : (s == 32);
        ushort_t* cb = sm + (s & 3) * 8192;
        short8 kb[4][2];
        #pragma unroll
        for (int m = 0; m < 4; ++m)
            #pragma unroll
            for (int i = 0; i < 2; ++i)
                kb[m][i] = *(const short8*)(cb + (m * 16 + cl) * 64 + ((i * 4 + qd) ^ swz) * 8);
        floatx4 sacc[4] = {z4, z4, z4, z4};
        #pragma unroll
        for (int i = 0; i < 2; ++i)
            #pragma unroll
            for (int m = 0; m < 4; ++m)
                sacc[m] = __builtin_amdgcn_mfma_f32_16x16x32_bf16(
                    kb[m][i], (i ? qf1 : qf0), sacc[m], 0, 0, 0);
        const int qabs = qw + cl;
        float pr[4][4];
        if (diag) {
            #pragma unroll
            for (int c = 0; c < 4; ++c)
                #pragma unroll
                for (int r = 0; r < 4; ++r) {
                    const bool keep = (kbase + c * 16 + qd * 4 + r) <= qabs;
                    const float e = __builtin_amdgcn_exp2f(sacc[c][r]);
                    pr[c][r] = keep ? e : 0.f;
                    l_ += pr[c][r];
                }
        } else {
            #pragma unroll
            for (int c = 0; c < 4; ++c)
                #pragma unroll
                for (int r = 0; r < 4; ++r) {
                    pr[c][r] = __builtin_amdgcn_exp2f(sacc[c][r]);
                    l_ += pr[c][r];
                }
        }
        short8 va2[4][2];
        #pragma unroll
        for (int dt = 0; dt < 4; ++dt)
            #pragma unroll
            for (int h2 = 0; h2 < 2; ++h2)
                va2[dt][h2] = *(const short8*)(cb + 4096 + (dt * 16 + cl) * 64 +
                                               ((qd * 2 + h2) ^ swz) * 8);
        #pragma unroll
        for (int cp = 0; cp < 2; ++cp) {
            union { uint_t u[4]; short8 v; } pb;
            pb.u[0] = pk_bf16(pr[cp * 2][0],     pr[cp * 2][1]);
            pb.u[1] = pk_bf16(pr[cp * 2][2],     pr[cp * 2][3]);
            pb.u[2] = pk_bf16(pr[cp * 2 + 1][0], pr[cp * 2 + 1][1]);
            pb.u[3] = pk_bf16(pr[cp * 2 + 1][2], pr[cp * 2 + 1][3]);
            #pragma unroll
            for (int dt = 0; dt < 4; ++dt)
                oaccT[dt] = __builtin_amdgcn_mfma_f32_16x16x32_bf16(
                    va2[dt][cp], pb.v, oaccT[dt], 0, 0, 0);
        }
        if (s == btA) {
            flush(qw);
            #pragma unroll
            for (int dt = 0; dt < 4; ++dt) oaccT[dt] = z4;
            l_ = 0.f;
            qw = p * 64 + wv * 16;
            qf0 = *(const short8*)(Qh + (size_t)(qw + cl) * DK_ + qd * 8);
            qf1 = *(const short8*)(Qh + (size_t)(qw + cl) * DK_ + 32 + qd * 8);
        }
    };

    for (int g = 0; g < 17; ++g) {
        const int s0 = g * 2;
        __syncthreads();
        if (s0 + 2 <= 32) stage_step(s0 + 2);
        if (s0 + 3 <= 32) stage_step(s0 + 3);
        compute_step(s0);
        if (s0 + 1 <= 32) compute_step(s0 + 1);
    }
    flush(qw);                           // tile B
}

// ---------------------------------------------------------------- launch
extern "C" void kernel_launch(void* const* d_in, const int* in_sizes, int n_in,
                              void* d_out, int out_size, void* d_ws, size_t ws_size,
                              hipStream_t stream)
{
    const float* q_in = (const float*)d_in[0];
    const float* k_in = (const float*)d_in[1];
    const float* v_in = (const float*)d_in[2];
    const float* Wq   = (const float*)d_in[3];
    const float* bq   = (const float*)d_in[4];
    const float* Wk   = (const float*)d_in[5];
    const float* bk   = (const float*)d_in[6];
    const float* Wv   = (const float*)d_in[7];
    const float* bv   = (const float*)d_in[8];
    const float* Wo   = (const float*)d_in[9];
    const float* bo   = (const float*)d_in[10];
    float* out = (float*)d_out;

    const size_t NTD = (size_t)B_ * T_ * D_;  // 4,194,304
    const size_t NW  = (size_t)D_ * D_;       // 1,048,576
    ushort_t* ws  = (ushort_t*)d_ws;
    ushort_t* Xq  = ws;
    ushort_t* Xk  = Xq + NTD;
    ushort_t* Xv  = Xk + NTD;
    ushort_t* Wqb = Xv + NTD;
    ushort_t* Wkb = Wqb + NW;
    ushort_t* Wvb = Wkb + NW;
    ushort_t* Wob = Wvb + NW;
    ushort_t* Qd  = Wob + NW;
    ushort_t* Kd  = Qd + NTD;
    ushort_t* Vtd = Kd + NTD;
    ushort_t* Od  = Vtd + NTD;

    const int total4 = (int)((3 * NTD + 4 * NW) / 4);   // 4,194,304
    cast_all_kernel<<<dim3(total4 / 256), dim3(256), 0, stream>>>(
        q_in, k_in, v_in, Wq, Wk, Wv, Wo,
        Xq, Xk, Xv, Wqb, Wkb, Wvb, Wob);

    gemm_qkv_kernel<<<dim3(32, 8, 3), dim3(256), 0, stream>>>(
        Xq, Xk, Xv, Wqb, Wkb, Wvb, bq, bk, bv, Qd, Kd, Vtd);

    attn_kernel<<<dim3(32, 16), dim3(256), 0, stream>>>(Qd, Kd, Vtd, Od);

    gemm_o_kernel<<<dim3(32, 8, 1), dim3(256), 0, stream>>>(Od, Wob, bo, out);
}

// Round 12
// 211.409 us; speedup vs baseline: 1.1748x; 1.0289x over previous
//
#include <hip/hip_runtime.h>
#include <hip/hip_bf16.h>
#include <stdint.h>

// Problem constants (ManualMHA): B=2, T=2048, D=1024, H=16, DK=64
#define B_   2
#define T_   2048
#define D_   1024
#define H_   16
#define DK_  64
#define KL2_ 0.18033688f   // SCALE * log2(e) = 0.125 * 1.4426950408889634

typedef __attribute__((ext_vector_type(8))) short   short8;   // 8 x bf16 (4 VGPRs)
typedef __attribute__((ext_vector_type(4))) float   floatx4;  // MFMA C/D
typedef unsigned short ushort_t;
typedef unsigned int   uint_t;

// ---------------------------------------------------------------- helpers
__device__ __forceinline__ ushort_t f32_to_bf16(float f) {
    union { float f; unsigned int u; } v; v.f = f;
    unsigned int r = v.u + 0x7fffu + ((v.u >> 16) & 1u);   // RNE
    return (ushort_t)(r >> 16);
}

// pack two fp32 -> (bf16(hi)<<16)|bf16(lo) with +0x8000 round bias, 3 VALU ops
__device__ __forceinline__ uint_t pk_bf16(float lo, float hi) {
    uint_t ulo = __builtin_bit_cast(uint_t, lo) + 0x8000u;
    uint_t uhi = __builtin_bit_cast(uint_t, hi) + 0x8000u;
    return __builtin_amdgcn_perm(uhi, ulo, 0x07060302);  // bytes: lo[2],lo[3],hi[2],hi[3]
}

__device__ __forceinline__ void async_copy16(const ushort_t* g, ushort_t* l) {
    typedef const unsigned int __attribute__((address_space(1)))* gp_t;
    typedef       unsigned int __attribute__((address_space(3)))* lp_t;
    __builtin_amdgcn_global_load_lds((gp_t)(uintptr_t)g, (lp_t)(uintptr_t)l, 16, 0, 0);
}

// ---------------------------------------------------------------- fused fp32 -> bf16 cast
__global__ __launch_bounds__(256) void cast_all_kernel(
    const float* __restrict__ q, const float* __restrict__ k, const float* __restrict__ v,
    const float* __restrict__ wq, const float* __restrict__ wk,
    const float* __restrict__ wv, const float* __restrict__ wo,
    ushort_t* __restrict__ oq, ushort_t* __restrict__ ok, ushort_t* __restrict__ ov,
    ushort_t* __restrict__ owq, ushort_t* __restrict__ owk,
    ushort_t* __restrict__ owv, ushort_t* __restrict__ owo)
{
    const int NTD4 = (B_ * T_ * D_) / 4;   // 1048576
    const int NW4  = (D_ * D_) / 4;        // 262144
    int i = blockIdx.x * 256 + threadIdx.x;
    const float* s; ushort_t* d; int off;
    if (i < NTD4)              { s = q; d = oq; off = i; }
    else if (i < 2 * NTD4)     { s = k; d = ok; off = i - NTD4; }
    else if (i < 3 * NTD4)     { s = v; d = ov; off = i - 2 * NTD4; }
    else {
        int w = i - 3 * NTD4;
        int seg = w / NW4;  off = w - seg * NW4;
        s = (seg == 0) ? wq : (seg == 1) ? wk : (seg == 2) ? wv : wo;
        d = (seg == 0) ? owq : (seg == 1) ? owk : (seg == 2) ? owv : owo;
    }
    float4 x = ((const float4*)s)[off];
    ushort4 o;
    o.x = f32_to_bf16(x.x); o.y = f32_to_bf16(x.y);
    o.z = f32_to_bf16(x.z); o.w = f32_to_bf16(x.w);
    ((ushort4*)d)[off] = o;
}

// ---------------------------------------------------------------- GEMM (C = A * W^T + bias)
// MODE 0: out fp32 [M,N]
// MODE 1: out bf16 scattered to [B,H,T,DK], scaled by oscale       (Q, K)
// MODE 2: out bf16 scattered to [B,H,DK,T] with t[5:4]<->t[3:2]    (V, attn A-frag layout)
// NI = B-tile width in 16-col units per wave-column: NI=4 -> BN=128, NI=2 -> BN=64.
//   NI=2 doubles the block count for small grids (gemm_o: 256 blocks = 1
//   block/CU had ZERO co-residency -> every barrier drain exposed raw).
//
// Structure = R8 (m97 2-barrier shape; 1-barrier dbuf regressed R9).
// Layout   = row-major [row][32] (coalesced staging: 4 lanes per 64B row
//            segment) + XOR chunk swizzle (R11, gemm_qkv 48 -> <40 us):
//   stage:  LDS slot c of row r holds global chunk c ^ ((r>>1)&3)
//   read:   fragment chunk' = qd ^ ((cl>>1)&3)
//   banks:  2 lanes per 4-bank group -> 2-way = free (m136)
#define BM 128
#define BK 32

template<int MODE, int NI>
__device__ __forceinline__ void gemm_bt_device(
    const ushort_t* __restrict__ A, const ushort_t* __restrict__ W,
    const float* __restrict__ bias, void* __restrict__ outp,
    int m0, int n0, ushort_t* sm, float oscale)
{
    const int tid  = threadIdx.x;
    const int lane = tid & 63;
    const int wv   = tid >> 6;
    const int wm   = (wv >> 1) * 64;
    const int wn   = (wv & 1) * (NI * 16);
    const int cl   = lane & 15;
    const int qd   = lane >> 4;
    const int sw4  = (cl >> 1) & 3;      // fragment-read chunk swizzle

    floatx4 acc[4][NI];
    const floatx4 z4 = {0.f, 0.f, 0.f, 0.f};
    #pragma unroll
    for (int mi = 0; mi < 4; ++mi)
        #pragma unroll
        for (int ni = 0; ni < NI; ++ni) acc[mi][ni] = z4;

    // staging: thread -> row r0 = tid>>2 (and r0+64 for 128-row operands),
    // slot c = tid&3; global chunk cg = c ^ ((r>>1)&3) (r and r+64 agree)
    const int r0 = tid >> 2;
    const int cg = (tid & 3) ^ ((r0 >> 1) & 3);
    const ushort_t* Ag0 = A + (size_t)(m0 + r0) * 1024 + cg * 8;
    const ushort_t* Ag1 = A + (size_t)(m0 + 64 + r0) * 1024 + cg * 8;
    const ushort_t* Wg0 = W + (size_t)(n0 + r0) * 1024 + cg * 8;
    const ushort_t* Wg1 = W + (size_t)(n0 + 64 + r0) * 1024 + cg * 8;
    ushort_t* As0 = sm + tid * 8;
    ushort_t* As1 = sm + 2048 + tid * 8;
    ushort_t* Bs0 = sm + 4096 + tid * 8;
    ushort_t* Bs1 = sm + 6144 + tid * 8;

    for (int k0 = 0; k0 < 1024; k0 += BK) {
        async_copy16(Ag0 + k0, As0);
        async_copy16(Ag1 + k0, As1);
        async_copy16(Wg0 + k0, Bs0);
        if (NI == 4) async_copy16(Wg1 + k0, Bs1);
        __syncthreads();

        short8 af[4], bfr[NI];
        #pragma unroll
        for (int mi = 0; mi < 4; ++mi)
            af[mi] = *(const short8*)(sm + (wm + mi * 16 + cl) * 32 + (qd ^ sw4) * 8);
        #pragma unroll
        for (int ni = 0; ni < NI; ++ni)
            bfr[ni] = *(const short8*)(sm + 4096 + (wn + ni * 16 + cl) * 32 + (qd ^ sw4) * 8);

        #pragma unroll
        for (int mi = 0; mi < 4; ++mi)
            #pragma unroll
            for (int ni = 0; ni < NI; ++ni)
                acc[mi][ni] = __builtin_amdgcn_mfma_f32_16x16x32_bf16(
                    af[mi], bfr[ni], acc[mi][ni], 0, 0, 0);
        __syncthreads();
    }

    // epilogue: C/D layout col = lane&15, row = (lane>>4)*4 + reg
    #pragma unroll
    for (int mi = 0; mi < 4; ++mi) {
        #pragma unroll
        for (int ni = 0; ni < NI; ++ni) {
            const int n = n0 + wn + ni * 16 + cl;
            const float bn = bias[n];
            if (MODE == 0) {
                float* out = (float*)outp;
                #pragma unroll
                for (int r = 0; r < 4; ++r) {
                    const int m = m0 + wm + mi * 16 + qd * 4 + r;
                    out[(size_t)m * D_ + n] = acc[mi][ni][r] + bn;
                }
            } else if (MODE == 1) {
                ushort_t* out = (ushort_t*)outp;
                const int h = n >> 6, dk = n & 63;
                #pragma unroll
                for (int r = 0; r < 4; ++r) {
                    const int m = m0 + wm + mi * 16 + qd * 4 + r;
                    const int b = m >> 11, t = m & (T_ - 1);
                    out[(((size_t)(b * H_ + h)) * T_ + t) * DK_ + dk] =
                        f32_to_bf16((acc[mi][ni][r] + bn) * oscale);
                }
            } else {
                ushort_t* out = (ushort_t*)outp;
                const int h = n >> 6, dk = n & 63;
                const int mb = m0 + wm + mi * 16 + qd * 4;  // 4 consecutive t, same b
                const int b = mb >> 11, t0 = mb & (T_ - 1);
                // swizzle t bits [5:4] <-> [3:2] so attention A-fragments are contiguous
                const int tsw = (t0 & ~60) | ((t0 & 48) >> 2) | ((t0 & 12) << 2);
                ushort4 o;
                o.x = f32_to_bf16(acc[mi][ni][0] + bn);
                o.y = f32_to_bf16(acc[mi][ni][1] + bn);
                o.z = f32_to_bf16(acc[mi][ni][2] + bn);
                o.w = f32_to_bf16(acc[mi][ni][3] + bn);
                *(ushort4*)(out + (((size_t)(b * H_ + h)) * DK_ + dk) * T_ + tsw) = o;
            }
        }
    }
}

__global__ __launch_bounds__(256) void gemm_qkv_kernel(
    const ushort_t* __restrict__ Xq, const ushort_t* __restrict__ Xk, const ushort_t* __restrict__ Xv,
    const ushort_t* __restrict__ Wq, const ushort_t* __restrict__ Wk, const ushort_t* __restrict__ Wv,
    const float* __restrict__ bq, const float* __restrict__ bk, const float* __restrict__ bv,
    ushort_t* __restrict__ Q, ushort_t* __restrict__ K, ushort_t* __restrict__ Vt)
{
    __shared__ __align__(16) ushort_t sm[8192];   // A 8KB + B 8KB (single buffer)
    const int m0 = blockIdx.x * BM, n0 = blockIdx.y * 128;
    // Q is pre-scaled by SCALE*log2(e) so attention's softmax is a bare exp2
    if (blockIdx.z == 0)      gemm_bt_device<1, 4>(Xq, Wq, bq, Q,  m0, n0, sm, KL2_);
    else if (blockIdx.z == 1) gemm_bt_device<1, 4>(Xk, Wk, bk, K,  m0, n0, sm, 1.0f);
    else                      gemm_bt_device<2, 4>(Xv, Wv, bv, Vt, m0, n0, sm, 1.0f);
}

// gemm_o: BN=64 (NI=2) -> 512 blocks = 2 blocks/CU co-resident (256 blocks
// at BN=128 was 1 block/CU: zero TLP, every barrier drain exposed).
__global__ __launch_bounds__(256) void gemm_o_kernel(
    const ushort_t* __restrict__ A, const ushort_t* __restrict__ W,
    const float* __restrict__ bias, float* __restrict__ out)
{
    __shared__ __align__(16) ushort_t sm[8192];
    gemm_bt_device<0, 2>(A, W, bias, out, blockIdx.x * BM, blockIdx.y * 64, sm, 1.0f);
}

// ---------------------------------------------------------------- flash attention
// (unchanged from R8 — 4 LDS buffers, two steps per barrier, pair-balanced)
__global__ __launch_bounds__(256, 2) void attn_kernel(
    const ushort_t* __restrict__ Q, const ushort_t* __restrict__ K,
    const ushort_t* __restrict__ Vs, ushort_t* __restrict__ O)
{
    __shared__ __align__(16) ushort_t sm[32768];  // 4 bufs x (K 4096 + V 4096)
    const int tid  = threadIdx.x;
    const int lane = tid & 63;
    const int wv   = tid >> 6;
    const int cl   = lane & 15;
    const int qd   = lane >> 4;
    const int swz  = cl & 7;
    const int h = blockIdx.x & (H_ - 1), b = blockIdx.x >> 4;
    const int p   = blockIdx.y;          // pair id 0..15
    const int btA = 31 - p;              // deep 64-row tile; tile B = p

    const ushort_t* Qh = Q  + ((size_t)(b * H_ + h) * T_) * DK_;
    const ushort_t* Kh = K  + ((size_t)(b * H_ + h) * T_) * DK_;
    const ushort_t* Vh = Vs + ((size_t)(b * H_ + h) * DK_) * T_;

    const int sr  = tid >> 3;
    const int sc  = tid & 7;
    const int scg = sc ^ (sr & 7);

    auto stage_step = [&](int s) {
        const int kbase = ((s <= btA) ? s : (s - btA - 1)) << 6;
        ushort_t* Kb = sm + (s & 3) * 8192;
        ushort_t* Vb = Kb + 4096;
        #pragma unroll
        for (int rr = 0; rr < 2; ++rr) {
            const int r = rr * 32 + sr;
            async_copy16(Kh + (size_t)(kbase + r) * DK_ + scg * 8, Kb + r * 64 + sc * 8);
            async_copy16(Vh + (size_t)r * T_ + kbase + scg * 8,    Vb + r * 64 + sc * 8);
        }
    };

    int qw = btA * 64 + wv * 16;         // wave's q-row base (current tile)
    short8 qf0 = *(const short8*)(Qh + (size_t)(qw + cl) * DK_ + qd * 8);
    short8 qf1 = *(const short8*)(Qh + (size_t)(qw + cl) * DK_ + 32 + qd * 8);

    stage_step(0);
    stage_step(1);

    const floatx4 z4 = {0.f, 0.f, 0.f, 0.f};
    floatx4 oaccT[4] = {z4, z4, z4, z4}; // O^T tiles: row = dk, col = q
    float l_ = 0.f;

    auto flush = [&](int q0w) {
        float l = l_;
        l += __shfl_xor(l, 16, 64);
        l += __shfl_xor(l, 32, 64);
        const float inv = 1.0f / l;
        ushort_t* Ob = O + ((size_t)(b * T_ + q0w + cl)) * D_ + h * DK_ + qd * 4;
        #pragma unroll
        for (int dt = 0; dt < 4; ++dt) {
            ushort4 o;
            o.x = f32_to_bf16(oaccT[dt][0] * inv);
            o.y = f32_to_bf16(oaccT[dt][1] * inv);
            o.z = f32_to_bf16(oaccT[dt][2] * inv);
            o.w = f32_to_bf16(oaccT[dt][3] * inv);
            *(ushort4*)(Ob + dt * 16) = o;
        }
    };

    auto compute_step = [&](int s) {
        const bool inA  = (s <= btA);
        const int kbase = (inA ? s : (s - btA - 1)) << 6;
        const bool diag = inA ? (s == btA) : (s == 32);
        ushort_t* cb = sm + (s & 3) * 8192;
        short8 kb[4][2];
        #pragma unroll
        for (int m = 0; m < 4; ++m)
            #pragma unroll
            for (int i = 0; i < 2; ++i)
                kb[m][i] = *(const short8*)(cb + (m * 16 + cl) * 64 + ((i * 4 + qd) ^ swz) * 8);
        floatx4 sacc[4] = {z4, z4, z4, z4};
        #pragma unroll
        for (int i = 0; i < 2; ++i)
            #pragma unroll
            for (int m = 0; m < 4; ++m)
                sacc[m] = __builtin_amdgcn_mfma_f32_16x16x32_bf16(
                    kb[m][i], (i ? qf1 : qf0), sacc[m], 0, 0, 0);
        const int qabs = qw + cl;
        float pr[4][4];
        if (diag) {
            #pragma unroll
            for (int c = 0; c < 4; ++c)
                #pragma unroll
                for (int r = 0; r < 4; ++r) {
                    const bool keep = (kbase + c * 16 + qd * 4 + r) <= qabs;
                    const float e = __builtin_amdgcn_exp2f(sacc[c][r]);
                    pr[c][r] = keep ? e : 0.f;
                    l_ += pr[c][r];
                }
        } else {
            #pragma unroll
            for (int c = 0; c < 4; ++c)
                #pragma unroll
                for (int r = 0; r < 4; ++r) {
                    pr[c][r] = __builtin_amdgcn_exp2f(sacc[c][r]);
                    l_ += pr[c][r];
                }
        }
        short8 va2[4][2];
        #pragma unroll
        for (int dt = 0; dt < 4; ++dt)
            #pragma unroll
            for (int h2 = 0; h2 < 2; ++h2)
                va2[dt][h2] = *(const short8*)(cb + 4096 + (dt * 16 + cl) * 64 +
                                               ((qd * 2 + h2) ^ swz) * 8);
        #pragma unroll
        for (int cp = 0; cp < 2; ++cp) {
            union { uint_t u[4]; short8 v; } pb;
            pb.u[0] = pk_bf16(pr[cp * 2][0],     pr[cp * 2][1]);
            pb.u[1] = pk_bf16(pr[cp * 2][2],     pr[cp * 2][3]);
            pb.u[2] = pk_bf16(pr[cp * 2 + 1][0], pr[cp * 2 + 1][1]);
            pb.u[3] = pk_bf16(pr[cp * 2 + 1][2], pr[cp * 2 + 1][3]);
            #pragma unroll
            for (int dt = 0; dt < 4; ++dt)
                oaccT[dt] = __builtin_amdgcn_mfma_f32_16x16x32_bf16(
                    va2[dt][cp], pb.v, oaccT[dt], 0, 0, 0);
        }
        if (s == btA) {
            flush(qw);
            #pragma unroll
            for (int dt = 0; dt < 4; ++dt) oaccT[dt] = z4;
            l_ = 0.f;
            qw = p * 64 + wv * 16;
            qf0 = *(const short8*)(Qh + (size_t)(qw + cl) * DK_ + qd * 8);
            qf1 = *(const short8*)(Qh + (size_t)(qw + cl) * DK_ + 32 + qd * 8);
        }
    };

    for (int g = 0; g < 17; ++g) {
        const int s0 = g * 2;
        __syncthreads();
        if (s0 + 2 <= 32) stage_step(s0 + 2);
        if (s0 + 3 <= 32) stage_step(s0 + 3);
        compute_step(s0);
        if (s0 + 1 <= 32) compute_step(s0 + 1);
    }
    flush(qw);                           // tile B
}

// ---------------------------------------------------------------- launch
extern "C" void kernel_launch(void* const* d_in, const int* in_sizes, int n_in,
                              void* d_out, int out_size, void* d_ws, size_t ws_size,
                              hipStream_t stream)
{
    const float* q_in = (const float*)d_in[0];
    const float* k_in = (const float*)d_in[1];
    const float* v_in = (const float*)d_in[2];
    const float* Wq   = (const float*)d_in[3];
    const float* bq   = (const float*)d_in[4];
    const float* Wk   = (const float*)d_in[5];
    const float* bk   = (const float*)d_in[6];
    const float* Wv   = (const float*)d_in[7];
    const float* bv   = (const float*)d_in[8];
    const float* Wo   = (const float*)d_in[9];
    const float* bo   = (const float*)d_in[10];
    float* out = (float*)d_out;

    const size_t NTD = (size_t)B_ * T_ * D_;  // 4,194,304
    const size_t NW  = (size_t)D_ * D_;       // 1,048,576
    ushort_t* ws  = (ushort_t*)d_ws;
    ushort_t* Xq  = ws;
    ushort_t* Xk  = Xq + NTD;
    ushort_t* Xv  = Xk + NTD;
    ushort_t* Wqb = Xv + NTD;
    ushort_t* Wkb = Wqb + NW;
    ushort_t* Wvb = Wkb + NW;
    ushort_t* Wob = Wvb + NW;
    ushort_t* Qd  = Wob + NW;
    ushort_t* Kd  = Qd + NTD;
    ushort_t* Vtd = Kd + NTD;
    ushort_t* Od  = Vtd + NTD;

    const int total4 = (int)((3 * NTD + 4 * NW) / 4);   // 4,194,304
    cast_all_kernel<<<dim3(total4 / 256), dim3(256), 0, stream>>>(
        q_in, k_in, v_in, Wq, Wk, Wv, Wo,
        Xq, Xk, Xv, Wqb, Wkb, Wvb, Wob);

    gemm_qkv_kernel<<<dim3(32, 8, 3), dim3(256), 0, stream>>>(
        Xq, Xk, Xv, Wqb, Wkb, Wvb, bq, bk, bv, Qd, Kd, Vtd);

    attn_kernel<<<dim3(32, 16), dim3(256), 0, stream>>>(Qd, Kd, Vtd, Od);

    gemm_o_kernel<<<dim3(32, 16), dim3(256), 0, stream>>>(Od, Wob, bo, out);
}